// Round 1
// 1083.923 us; speedup vs baseline: 1.0218x; 1.0218x over previous
//
#include <hip/hip_runtime.h>

// ---------- helpers ----------
static __device__ __forceinline__ unsigned short f2bf(float f) {
  union { float f; unsigned u; } v; v.f = f;
  unsigned r = v.u + 0x7fffu + ((v.u >> 16) & 1u);
  return (unsigned short)(r >> 16);
}

struct alignas(8) us4 { unsigned short x, y, z, w; };

typedef __bf16 bf16x8 __attribute__((ext_vector_type(8)));
typedef float f32x4 __attribute__((ext_vector_type(4)));

static __device__ __forceinline__ void load_lds16(const void* g, void* l) {
  __builtin_amdgcn_global_load_lds(
      (const __attribute__((address_space(1))) unsigned int*)g,
      (__attribute__((address_space(3))) unsigned int*)l,
      16, 0, 0);
}

static __device__ __forceinline__ float block_sum(float v, float* sred) {
  #pragma unroll
  for (int o = 32; o > 0; o >>= 1) v += __shfl_down(v, o, 64);
  const int tid = threadIdx.x;
  __syncthreads();
  if ((tid & 63) == 0) sred[tid >> 6] = v;
  __syncthreads();
  return sred[0] + sred[1] + sred[2] + sred[3];
}

// ---------- kernel 1: embedding gather + two RMSNorms -> u (bf16 [4096][1024]) ----------
__global__ __launch_bounds__(256) void embed_norm(
    const int* __restrict__ ids, const float* __restrict__ emb,
    const float* __restrict__ w1, const float* __restrict__ w2,
    unsigned short* __restrict__ u_bf)
{
  __shared__ float sred[4];
  const int row = blockIdx.x;
  const int tid = threadIdx.x;
  const int id = ids[row];
  const float4 e = *(const float4*)(emb + (size_t)id * 1024 + tid * 4);
  float tot = block_sum(e.x*e.x + e.y*e.y + e.z*e.z + e.w*e.w, sred);
  float inv1 = rsqrtf(tot * (1.0f/1024.0f) + 1e-6f);
  const float4 a = *(const float4*)(w1 + tid * 4);
  float x0 = e.x*inv1*a.x, x1 = e.y*inv1*a.y, x2 = e.z*inv1*a.z, x3 = e.w*inv1*a.w;
  float tot2 = block_sum(x0*x0 + x1*x1 + x2*x2 + x3*x3, sred);
  float inv2 = rsqrtf(tot2 * (1.0f/1024.0f) + 1e-6f);
  const float4 b = *(const float4*)(w2 + tid * 4);
  us4 o;
  o.x = f2bf(x0*inv2*b.x); o.y = f2bf(x1*inv2*b.y);
  o.z = f2bf(x2*inv2*b.z); o.w = f2bf(x3*inv2*b.w);
  *(us4*)(u_bf + (size_t)row * 1024 + tid * 4) = o;
}

// ---------- pack kernels: build K-contiguous (transposed) bf16 B-operands ----------
// BcatT [512][1024]: rows 0..255 = B_re columns, 256..511 = B_im columns
__global__ __launch_bounds__(256) void pack_B(
    const float* __restrict__ B_re, const float* __restrict__ B_im,
    unsigned short* __restrict__ BT)
{
  int t = blockIdx.x * 256 + threadIdx.x;    // 512*1024
  int n = t >> 10, k = t & 1023;
  float v = (n < 256) ? B_re[(size_t)k * 256 + n] : B_im[(size_t)k * 256 + (n - 256)];
  BT[t] = f2bf(v);
}

// CcatT [1024][512]: CcatT[d][s] = C_re[s][d] (s<256), = -C_im[s-256][d] (s>=256)
__global__ __launch_bounds__(256) void pack_C(
    const float* __restrict__ C_re, const float* __restrict__ C_im,
    unsigned short* __restrict__ CT)
{
  int t = blockIdx.x * 256 + threadIdx.x;    // 1024*512
  int d = t >> 9, sc = t & 511;
  float v = (sc < 256) ? C_re[(size_t)sc * 1024 + d] : -C_im[(size_t)(sc - 256) * 1024 + d];
  CT[t] = f2bf(v);
}

// head_w fp32 [1024][32000] -> head_wT bf16 [32000][1024] via LDS tile transpose
__global__ __launch_bounds__(256) void transpose_cvt(
    const float* __restrict__ in, unsigned short* __restrict__ out, int Kd, int Nd)
{
  __shared__ float tile[32][33];
  const int n0 = blockIdx.x * 32, k0 = blockIdx.y * 32;
  const int tx = threadIdx.x, ty = threadIdx.y;
  #pragma unroll
  for (int j = 0; j < 32; j += 8)
    tile[ty + j][tx] = in[(size_t)(k0 + ty + j) * Nd + n0 + tx];
  __syncthreads();
  #pragma unroll
  for (int j = 0; j < 32; j += 8)
    out[(size_t)(n0 + ty + j) * Kd + k0 + tx] = f2bf(tile[tx][ty + j]);
}

// ---------- MFMA GEMM: out[M][N] = A[M][K] @ BT[N][K]^T (+bias) ----------
// 1D grid; bijective XCD-chunk swizzle (m204) + m-fastest tile order so the
// blocks sharing one 256 KB B-panel run consecutively on ONE XCD (B-panel
// stays L2-resident across its 32 uses; B's n-range partitioned across XCDs).
template<bool OUT_BF16, bool HAS_BIAS, bool NT_STORE>
__global__ __launch_bounds__(256) void gemm_bt(
    const unsigned short* __restrict__ A,
    const unsigned short* __restrict__ BT,
    const float* __restrict__ bias,
    void* __restrict__ outp,
    int M, int N, int K)
{
  __shared__ unsigned short As[128 * 32];
  __shared__ unsigned short Bs[128 * 32];
  const int tid = threadIdx.x;
  const int lane = tid & 63;
  const int wave = tid >> 6;

  // --- XCD-chunked bijective remap: bid -> g (contiguous per XCD) ---
  const int nwg = gridDim.x;
  const int bid = blockIdx.x;
  const int q = nwg >> 3, r = nwg & 7;
  const int xcd = bid & 7, loc = bid >> 3;
  const int g = (xcd < r ? xcd * (q + 1) : r * (q + 1) + (xcd - r) * q) + loc;
  // m-fastest within a chunk: consecutive g share the same B n-tile
  const int nMt = M >> 7;
  const int mt = g % nMt;
  const int nt = g / nMt;
  const int m0 = mt << 7;
  const int n0 = nt << 7;

  const int wm = (wave >> 1) * 64;
  const int wn = (wave & 1) * 64;

  f32x4 acc[4][4] = {};

  const int lin0 = wave * 64 + lane;       // 0..255
  const int rowS = lin0 >> 2;              // staging row 0..63
  const int koS = (lin0 & 3) * 8;          // k offset 0/8/16/24
  const int aq = lane >> 4;
  const int al = lane & 15;

  for (int k0 = 0; k0 < K; k0 += 32) {
    load_lds16(A  + (size_t)(m0 + rowS)      * K + k0 + koS, As + (size_t)lin0 * 8);
    load_lds16(A  + (size_t)(m0 + 64 + rowS) * K + k0 + koS, As + (size_t)(256 + lin0) * 8);
    load_lds16(BT + (size_t)(n0 + rowS)      * K + k0 + koS, Bs + (size_t)lin0 * 8);
    load_lds16(BT + (size_t)(n0 + 64 + rowS) * K + k0 + koS, Bs + (size_t)(256 + lin0) * 8);
    __syncthreads();
    const bf16x8* Ap = (const bf16x8*)As;
    const bf16x8* Bp = (const bf16x8*)Bs;
    bf16x8 af[4], bfr[4];
    #pragma unroll
    for (int i = 0; i < 4; ++i) af[i] = Ap[(wm + i * 16 + al) * 4 + aq];
    #pragma unroll
    for (int j = 0; j < 4; ++j) bfr[j] = Bp[(wn + j * 16 + al) * 4 + aq];
    #pragma unroll
    for (int i = 0; i < 4; ++i)
      #pragma unroll
      for (int j = 0; j < 4; ++j)
        acc[i][j] = __builtin_amdgcn_mfma_f32_16x16x32_bf16(af[i], bfr[j], acc[i][j], 0, 0, 0);
    __syncthreads();
  }

  const int row0 = m0 + wm + (lane >> 4) * 4;
  const int col0 = n0 + wn + al;
  #pragma unroll
  for (int j = 0; j < 4; ++j) {
    const int col = col0 + j * 16;
    float bv = 0.f;
    if (HAS_BIAS) bv = bias[col];
    #pragma unroll
    for (int i = 0; i < 4; ++i) {
      #pragma unroll
      for (int r2 = 0; r2 < 4; ++r2) {
        float v = acc[i][j][r2] + bv;
        size_t o = (size_t)(row0 + i * 16 + r2) * N + col;
        if (OUT_BF16) {
          ((unsigned short*)outp)[o] = f2bf(v);
        } else if (NT_STORE) {
          __builtin_nontemporal_store(v, (float*)outp + o);
        } else {
          ((float*)outp)[o] = v;
        }
      }
    }
  }
}

// ---------- scan kernels: xs[l] = A*xs[l-1] + uB[l], chunked (16 chunks of 128) ----------
// uB layout fp32 [4096][512]: re at col s, im at col 256+s. Scan done in place.
__global__ __launch_bounds__(256) void local_scan(
    float* __restrict__ xs, float* __restrict__ carry,
    const float* __restrict__ A_re, const float* __restrict__ A_im)
{
  int t = blockIdx.x * 256 + threadIdx.x;  // 8192 = B(2)*chunks(16)*S(256)
  int s = t & 255;
  int chunk = (t >> 8) & 15;
  int b = t >> 12;
  float ar = A_re[s], ai = A_im[s];
  float xr = 0.f, xi = 0.f;
  size_t base = ((size_t)(b * 2048 + chunk * 128)) * 512 + s;
  for (int j = 0; j < 128; ++j) {
    float ur = xs[base], ui = xs[base + 256];
    float nr = fmaf(ar, xr, fmaf(-ai, xi, ur));
    float ni = fmaf(ar, xi, fmaf(ai, xr, ui));
    xs[base] = nr; xs[base + 256] = ni;
    xr = nr; xi = ni;
    base += 512;
  }
  int ci = (b * 16 + chunk) * 512 + s;
  carry[ci] = xr; carry[ci + 256] = xi;
}

// one block: A-power table (t=0..128) + exclusive carry prefix over chunks
__global__ __launch_bounds__(256) void carry_scan(
    const float* __restrict__ A_re, const float* __restrict__ A_im,
    const float* __restrict__ carry, float* __restrict__ state_before,
    float* __restrict__ Apow)
{
  int s = threadIdx.x;  // 0..255
  float ar = A_re[s], ai = A_im[s];
  float pr = 1.f, pi = 0.f;
  for (int t = 0; t <= 128; ++t) {
    Apow[t * 512 + s] = pr; Apow[t * 512 + 256 + s] = pi;
    float nr = pr * ar - pi * ai;
    float ni = pr * ai + pi * ar;
    pr = nr; pi = ni;
  }
  float cr = Apow[128 * 512 + s], ci = Apow[128 * 512 + 256 + s];  // A^128
  for (int b = 0; b < 2; ++b) {
    float str = 0.f, sti = 0.f;
    for (int c = 0; c < 16; ++c) {
      int idx = (b * 16 + c) * 512 + s;
      state_before[idx] = str; state_before[idx + 256] = sti;
      float lr = carry[idx], li = carry[idx + 256];
      float nr = lr + cr * str - ci * sti;
      float ni = li + cr * sti + ci * str;
      str = nr; sti = ni;
    }
  }
}

// xs_full = xs_local + A^(j+1)*state_before; cast to bf16 (re||im per row)
__global__ __launch_bounds__(256) void combine_cast(
    const float* __restrict__ xs, const float* __restrict__ state_before,
    const float* __restrict__ Apow, unsigned short* __restrict__ xs_cat)
{
  int t = blockIdx.x * 256 + threadIdx.x;  // 4096*256
  int s = t & 255, row = t >> 8;
  int l = row & 2047, b = row >> 11;
  int chunk = l >> 7, j = l & 127;
  size_t o = (size_t)row * 512 + s;
  float xr = xs[o], xi = xs[o + 256];
  int sbi = (b * 16 + chunk) * 512 + s;
  float sr = state_before[sbi], si = state_before[sbi + 256];
  int api = (j + 1) * 512 + s;
  float pr = Apow[api], pi = Apow[api + 256];
  float fr = xr + pr * sr - pi * si;
  float fi = xi + pr * si + pi * sr;
  xs_cat[o] = f2bf(fr); xs_cat[o + 256] = f2bf(fi);
}

// ---------- launch ----------
extern "C" void kernel_launch(void* const* d_in, const int* in_sizes, int n_in,
                              void* d_out, int out_size, void* d_ws, size_t ws_size,
                              hipStream_t stream) {
  (void)in_sizes; (void)n_in; (void)out_size; (void)ws_size;
  const int*   ids    = (const int*)d_in[0];
  const float* emb    = (const float*)d_in[1];
  const float* w1     = (const float*)d_in[2];
  const float* w2     = (const float*)d_in[3];
  const float* A_re   = (const float*)d_in[4];
  const float* A_im   = (const float*)d_in[5];
  const float* B_re   = (const float*)d_in[6];
  const float* B_im   = (const float*)d_in[7];
  const float* C_re   = (const float*)d_in[8];
  const float* C_im   = (const float*)d_in[9];
  const float* D_p    = (const float*)d_in[10];
  const float* head_w = (const float*)d_in[11];
  const float* head_b = (const float*)d_in[12];
  float* out = (float*)d_out;

  // scratch temps live in the front of d_out (dead before the head GEMM
  // overwrites all 524 MB of d_out); persistent-to-the-end buffers in d_ws.
  char* ob = (char*)d_out;
  unsigned short* u_bf   = (unsigned short*)(ob + 0);         //  8,388,608 B
  unsigned short* BcatT  = (unsigned short*)(ob + 8388608);   //  1,048,576 B
  float* uBxs            = (float*)(ob + 9437184);            //  8,388,608 B
  float* carry           = (float*)(ob + 17825792);           //     65,536 B
  float* state_before    = (float*)(ob + 17891328);           //     65,536 B
  float* Apow            = (float*)(ob + 17956864);           //    264,192 B
  unsigned short* xs_cat = (unsigned short*)(ob + 18221056);  //  4,194,304 B
  unsigned short* CcatT  = (unsigned short*)(ob + 22415360);  //  1,048,576 B

  char* wb = (char*)d_ws;
  unsigned short* head_wT = (unsigned short*)(wb + 0);        // 65,536,000 B
  unsigned short* y_bf    = (unsigned short*)(wb + 65536000); //  8,388,608 B

  embed_norm<<<4096, 256, 0, stream>>>(ids, emb, w1, w2, u_bf);
  pack_B<<<2048, 256, 0, stream>>>(B_re, B_im, BcatT);
  pack_C<<<2048, 256, 0, stream>>>(C_re, C_im, CcatT);
  transpose_cvt<<<dim3(1000, 32), dim3(32, 8), 0, stream>>>(head_w, head_wT, 1024, 32000);

  // uB = u @ Bcat   [4096,1024]x[1024,512] -> fp32 (cached; consumed by scan)
  gemm_bt<false, false, false><<<128, 256, 0, stream>>>(u_bf, BcatT, nullptr, uBxs, 4096, 512, 1024);

  local_scan<<<32, 256, 0, stream>>>(uBxs, carry, A_re, A_im);
  carry_scan<<<1, 256, 0, stream>>>(A_re, A_im, carry, state_before, Apow);
  combine_cast<<<4096, 256, 0, stream>>>(uBxs, state_before, Apow, xs_cat);

  // y = Re(xs @ C) + D_p   [4096,512]x[512,1024] -> bf16
  gemm_bt<true, true, false><<<256, 256, 0, stream>>>(xs_cat, CcatT, D_p, y_bf, 4096, 1024, 512);

  // out = y @ head_w + head_b   [4096,1024]x[1024,32000] -> fp32, nt stores
  gemm_bt<false, true, true><<<8000, 256, 0, stream>>>(y_bf, head_wT, head_b, out, 4096, 32000, 1024);
}

// Round 2
// 1060.318 us; speedup vs baseline: 1.0445x; 1.0223x over previous
//
#include <hip/hip_runtime.h>

// ---------- helpers ----------
static __device__ __forceinline__ unsigned short f2bf(float f) {
  union { float f; unsigned u; } v; v.f = f;
  unsigned r = v.u + 0x7fffu + ((v.u >> 16) & 1u);
  return (unsigned short)(r >> 16);
}

struct alignas(8) us4 { unsigned short x, y, z, w; };

typedef __bf16 bf16x8 __attribute__((ext_vector_type(8)));
typedef float f32x4 __attribute__((ext_vector_type(4)));

static __device__ __forceinline__ void load_lds16(const void* g, void* l) {
  __builtin_amdgcn_global_load_lds(
      (const __attribute__((address_space(1))) unsigned int*)g,
      (__attribute__((address_space(3))) unsigned int*)l,
      16, 0, 0);
}

static __device__ __forceinline__ float block_sum(float v, float* sred) {
  #pragma unroll
  for (int o = 32; o > 0; o >>= 1) v += __shfl_down(v, o, 64);
  const int tid = threadIdx.x;
  __syncthreads();
  if ((tid & 63) == 0) sred[tid >> 6] = v;
  __syncthreads();
  return sred[0] + sred[1] + sred[2] + sred[3];
}

// ---------- kernel 1: embedding gather + two RMSNorms -> u (bf16 [4096][1024]) ----------
__global__ __launch_bounds__(256) void embed_norm(
    const int* __restrict__ ids, const float* __restrict__ emb,
    const float* __restrict__ w1, const float* __restrict__ w2,
    unsigned short* __restrict__ u_bf)
{
  __shared__ float sred[4];
  const int row = blockIdx.x;
  const int tid = threadIdx.x;
  const int id = ids[row];
  const float4 e = *(const float4*)(emb + (size_t)id * 1024 + tid * 4);
  float tot = block_sum(e.x*e.x + e.y*e.y + e.z*e.z + e.w*e.w, sred);
  float inv1 = rsqrtf(tot * (1.0f/1024.0f) + 1e-6f);
  const float4 a = *(const float4*)(w1 + tid * 4);
  float x0 = e.x*inv1*a.x, x1 = e.y*inv1*a.y, x2 = e.z*inv1*a.z, x3 = e.w*inv1*a.w;
  float tot2 = block_sum(x0*x0 + x1*x1 + x2*x2 + x3*x3, sred);
  float inv2 = rsqrtf(tot2 * (1.0f/1024.0f) + 1e-6f);
  const float4 b = *(const float4*)(w2 + tid * 4);
  us4 o;
  o.x = f2bf(x0*inv2*b.x); o.y = f2bf(x1*inv2*b.y);
  o.z = f2bf(x2*inv2*b.z); o.w = f2bf(x3*inv2*b.w);
  *(us4*)(u_bf + (size_t)row * 1024 + tid * 4) = o;
}

// ---------- pack kernels ----------
__global__ __launch_bounds__(256) void pack_B(
    const float* __restrict__ B_re, const float* __restrict__ B_im,
    unsigned short* __restrict__ BT)
{
  int t = blockIdx.x * 256 + threadIdx.x;    // 512*1024
  int n = t >> 10, k = t & 1023;
  float v = (n < 256) ? B_re[(size_t)k * 256 + n] : B_im[(size_t)k * 256 + (n - 256)];
  BT[t] = f2bf(v);
}

__global__ __launch_bounds__(256) void pack_C(
    const float* __restrict__ C_re, const float* __restrict__ C_im,
    unsigned short* __restrict__ CT)
{
  int t = blockIdx.x * 256 + threadIdx.x;    // 1024*512
  int d = t >> 9, sc = t & 511;
  float v = (sc < 256) ? C_re[(size_t)sc * 1024 + d] : -C_im[(size_t)(sc - 256) * 1024 + d];
  CT[t] = f2bf(v);
}

__global__ __launch_bounds__(256) void transpose_cvt(
    const float* __restrict__ in, unsigned short* __restrict__ out, int Kd, int Nd)
{
  __shared__ float tile[32][33];
  const int n0 = blockIdx.x * 32, k0 = blockIdx.y * 32;
  const int tx = threadIdx.x, ty = threadIdx.y;
  #pragma unroll
  for (int j = 0; j < 32; j += 8)
    tile[ty + j][tx] = in[(size_t)(k0 + ty + j) * Nd + n0 + tx];
  __syncthreads();
  #pragma unroll
  for (int j = 0; j < 32; j += 8)
    out[(size_t)(n0 + ty + j) * Kd + k0 + tx] = f2bf(tile[tx][ty + j]);
}

// ---------- 128x128 MFMA GEMM (for the small GEMMs) ----------
template<bool OUT_BF16, bool HAS_BIAS>
__global__ __launch_bounds__(256) void gemm_bt(
    const unsigned short* __restrict__ A,
    const unsigned short* __restrict__ BT,
    const float* __restrict__ bias,
    void* __restrict__ outp,
    int M, int N, int K)
{
  __shared__ unsigned short As[128 * 32];
  __shared__ unsigned short Bs[128 * 32];
  const int tid = threadIdx.x;
  const int lane = tid & 63;
  const int wave = tid >> 6;

  const int nwg = gridDim.x;
  const int bid = blockIdx.x;
  const int q = nwg >> 3, r = nwg & 7;
  const int xcd = bid & 7, loc = bid >> 3;
  const int g = (xcd < r ? xcd * (q + 1) : r * (q + 1) + (xcd - r) * q) + loc;
  const int nMt = M >> 7;
  const int mt = g % nMt;
  const int nt = g / nMt;
  const int m0 = mt << 7;
  const int n0 = nt << 7;

  const int wm = (wave >> 1) * 64;
  const int wn = (wave & 1) * 64;

  f32x4 acc[4][4] = {};

  const int lin0 = wave * 64 + lane;
  const int rowS = lin0 >> 2;
  const int koS = (lin0 & 3) * 8;
  const int aq = lane >> 4;
  const int al = lane & 15;

  for (int k0 = 0; k0 < K; k0 += 32) {
    load_lds16(A  + (size_t)(m0 + rowS)      * K + k0 + koS, As + (size_t)lin0 * 8);
    load_lds16(A  + (size_t)(m0 + 64 + rowS) * K + k0 + koS, As + (size_t)(256 + lin0) * 8);
    load_lds16(BT + (size_t)(n0 + rowS)      * K + k0 + koS, Bs + (size_t)lin0 * 8);
    load_lds16(BT + (size_t)(n0 + 64 + rowS) * K + k0 + koS, Bs + (size_t)(256 + lin0) * 8);
    __syncthreads();
    const bf16x8* Ap = (const bf16x8*)As;
    const bf16x8* Bp = (const bf16x8*)Bs;
    bf16x8 af[4], bfr[4];
    #pragma unroll
    for (int i = 0; i < 4; ++i) af[i] = Ap[(wm + i * 16 + al) * 4 + aq];
    #pragma unroll
    for (int j = 0; j < 4; ++j) bfr[j] = Bp[(wn + j * 16 + al) * 4 + aq];
    #pragma unroll
    for (int i = 0; i < 4; ++i)
      #pragma unroll
      for (int j = 0; j < 4; ++j)
        acc[i][j] = __builtin_amdgcn_mfma_f32_16x16x32_bf16(af[i], bfr[j], acc[i][j], 0, 0, 0);
    __syncthreads();
  }

  const int row0 = m0 + wm + (lane >> 4) * 4;
  const int col0 = n0 + wn + al;
  #pragma unroll
  for (int j = 0; j < 4; ++j) {
    const int col = col0 + j * 16;
    float bv = 0.f;
    if (HAS_BIAS) bv = bias[col];
    #pragma unroll
    for (int i = 0; i < 4; ++i) {
      #pragma unroll
      for (int r2 = 0; r2 < 4; ++r2) {
        float v = acc[i][j][r2] + bv;
        size_t o = (size_t)(row0 + i * 16 + r2) * N + col;
        if (OUT_BF16) ((unsigned short*)outp)[o] = f2bf(v);
        else          ((float*)outp)[o] = v;
      }
    }
  }
}

// ---------- 256x256 8-phase MFMA GEMM (head) ----------
// T1 XCD swizzle + T2 LDS XOR-swizzle (pre-swizzled global source, swizzled
// ds_read) + T3/T4 8-phase with counted vmcnt(4) + T5 setprio.
// Staging schedule per iteration (tiles t->buf0, t+1->buf1), 1 half-tile/phase:
//   ph1:(t+1).Ah0  ph2:(t+1).Ah1  ph3:(t+2).Bh0  ph4:(t+2).Bh1 [vmcnt(4)]
//   ph5:(t+2).Ah0  ph6:(t+2).Ah1  ph7:(t+3).Bh0  ph8:(t+3).Bh1 [vmcnt(4)]
// Safety: B region of a buffer is last read at its ph2 (jh1), A at its ph3
// (ih1); every stage lands strictly after the barrier following those reads.
template<bool OUT_BF16, bool HAS_BIAS>
__global__ __launch_bounds__(512, 2) void gemm256_bt(
    const unsigned short* __restrict__ A,
    const unsigned short* __restrict__ BT,
    const float* __restrict__ bias,
    void* __restrict__ outp,
    int M, int N, int K)
{
  __shared__ unsigned short As[2][16384];
  __shared__ unsigned short Bs[2][16384];
  const int tid = threadIdx.x;
  const int lane = tid & 63;
  const int wave = tid >> 6;
  const int wr = wave >> 2;        // 0..1
  const int wc = wave & 3;         // 0..3

  const int nwg = gridDim.x;
  const int bid = blockIdx.x;
  const int q8 = nwg >> 3, r8 = nwg & 7;
  const int xcd = bid & 7, loc = bid >> 3;
  const int g = (xcd < r8 ? xcd * (q8 + 1) : r8 * (q8 + 1) + (xcd - r8) * q8) + loc;
  const int nMt = M >> 8;
  const int mt = g % nMt, ntile = g / nMt;
  const int m0 = mt << 8, n0 = ntile << 8;

  // staging source addresses, pre-swizzled: physical 16B slot p of row r holds
  // logical k-slot (p ^ (r&7)); gload_lds dest stays linear.
  const int s1i = tid + 512;
  const int ra0 = tid >> 3, ra1 = s1i >> 3;
  const size_t aoff0 = (size_t)ra0 * K + 8 * ((tid & 7) ^ (ra0 & 7));
  const size_t aoff1 = (size_t)ra1 * K + 8 * ((s1i & 7) ^ (ra1 & 7));
  const unsigned short* Ag0 = A + (size_t)m0 * K + aoff0;
  const unsigned short* Ag1 = A + (size_t)m0 * K + aoff1;
  const unsigned short* Bg0 = BT + (size_t)n0 * K + aoff0;
  const unsigned short* Bg1 = BT + (size_t)n0 * K + aoff1;
  const size_t hstep = (size_t)128 * K;

  const int al = lane & 15, aq = lane >> 4;
  const int arow = wr * 128 + al;
  const int brow = wc * 64 + al;
  const int sw0 = ((aq) ^ (al & 7)) << 4;       // ks=0 swizzled slot byte
  const int sw1 = ((4 + aq) ^ (al & 7)) << 4;   // ks=1

  f32x4 acc[8][4] = {};
  bf16x8 af[4][2];
  bf16x8 bfr[4][2];

  const int nT = K >> 6;   // K-tiles of 64 (even, >= 4)

#define STAGE_A_(b, h, tt) do { \
    load_lds16(Ag0 + (size_t)(h) * hstep + (size_t)(tt) * 64, &As[b][(h) * 8192 + tid * 8]); \
    load_lds16(Ag1 + (size_t)(h) * hstep + (size_t)(tt) * 64, &As[b][(h) * 8192 + 4096 + tid * 8]); \
  } while (0)
#define STAGE_B_(b, h, tt) do { \
    load_lds16(Bg0 + (size_t)(h) * hstep + (size_t)(tt) * 64, &Bs[b][(h) * 8192 + tid * 8]); \
    load_lds16(Bg1 + (size_t)(h) * hstep + (size_t)(tt) * 64, &Bs[b][(h) * 8192 + 4096 + tid * 8]); \
  } while (0)
#define DSRD_A_(b, ih) do { \
    const char* p_ = (const char*)As[b] + ((size_t)(arow + (ih) * 64) << 7); \
    af[0][0] = *(const bf16x8*)(p_ + sw0);        af[0][1] = *(const bf16x8*)(p_ + sw1); \
    af[1][0] = *(const bf16x8*)(p_ + 2048 + sw0); af[1][1] = *(const bf16x8*)(p_ + 2048 + sw1); \
    af[2][0] = *(const bf16x8*)(p_ + 4096 + sw0); af[2][1] = *(const bf16x8*)(p_ + 4096 + sw1); \
    af[3][0] = *(const bf16x8*)(p_ + 6144 + sw0); af[3][1] = *(const bf16x8*)(p_ + 6144 + sw1); \
  } while (0)
#define DSRD_B_(b, jh) do { \
    const char* p_ = (const char*)Bs[b] + ((size_t)(brow + (jh) * 32) << 7); \
    bfr[(jh)*2+0][0] = *(const bf16x8*)(p_ + sw0);        bfr[(jh)*2+0][1] = *(const bf16x8*)(p_ + sw1); \
    bfr[(jh)*2+1][0] = *(const bf16x8*)(p_ + 2048 + sw0); bfr[(jh)*2+1][1] = *(const bf16x8*)(p_ + 2048 + sw1); \
  } while (0)
#define MMA_Q_(ih, jh) do { \
    _Pragma("unroll") for (int i_ = 0; i_ < 4; ++i_) { \
      _Pragma("unroll") for (int j_ = 0; j_ < 2; ++j_) { \
        f32x4 c_ = acc[(ih)*4+i_][(jh)*2+j_]; \
        c_ = __builtin_amdgcn_mfma_f32_16x16x32_bf16(af[i_][0], bfr[(jh)*2+j_][0], c_, 0, 0, 0); \
        c_ = __builtin_amdgcn_mfma_f32_16x16x32_bf16(af[i_][1], bfr[(jh)*2+j_][1], c_, 0, 0, 0); \
        acc[(ih)*4+i_][(jh)*2+j_] = c_; \
      } \
    } \
  } while (0)
#define BARx() do { asm volatile("" ::: "memory"); __builtin_amdgcn_s_barrier(); asm volatile("" ::: "memory"); } while (0)
#define VMW4() asm volatile("s_waitcnt vmcnt(4)" ::: "memory")
#define VMW0() asm volatile("s_waitcnt vmcnt(0)" ::: "memory")
#define PRIO1() __builtin_amdgcn_s_setprio(1)
#define PRIO0() __builtin_amdgcn_s_setprio(0)

  // prologue: tile0 -> buf0, tile1.B -> buf1
  STAGE_A_(0, 0, 0); STAGE_A_(0, 1, 0);
  STAGE_B_(0, 0, 0); STAGE_B_(0, 1, 0);
  STAGE_B_(1, 0, 1); STAGE_B_(1, 1, 1);
  VMW4();
  BARx();

  for (int t = 0; t + 3 < nT; t += 2) {
    // ---- tile t (buf0) ----
    DSRD_A_(0, 0); DSRD_B_(0, 0);
    STAGE_A_(1, 0, t + 1);
    BARx(); PRIO1(); MMA_Q_(0, 0); PRIO0(); BARx();

    DSRD_B_(0, 1);
    STAGE_A_(1, 1, t + 1);
    BARx(); PRIO1(); MMA_Q_(0, 1); PRIO0(); BARx();

    DSRD_A_(0, 1);
    STAGE_B_(0, 0, t + 2);
    BARx(); PRIO1(); MMA_Q_(1, 0); PRIO0(); BARx();

    STAGE_B_(0, 1, t + 2);
    BARx(); PRIO1(); MMA_Q_(1, 1); PRIO0();
    VMW4();
    BARx();

    // ---- tile t+1 (buf1) ----
    DSRD_A_(1, 0); DSRD_B_(1, 0);
    STAGE_A_(0, 0, t + 2);
    BARx(); PRIO1(); MMA_Q_(0, 0); PRIO0(); BARx();

    DSRD_B_(1, 1);
    STAGE_A_(0, 1, t + 2);
    BARx(); PRIO1(); MMA_Q_(0, 1); PRIO0(); BARx();

    DSRD_A_(1, 1);
    STAGE_B_(1, 0, t + 3);
    BARx(); PRIO1(); MMA_Q_(1, 0); PRIO0(); BARx();

    STAGE_B_(1, 1, t + 3);
    BARx(); PRIO1(); MMA_Q_(1, 1); PRIO0();
    VMW4();
    BARx();
  }

  // ---- final pair: tiles nT-2 (buf0), nT-1 (buf1) ----
  {
    const int t = nT - 2;
    DSRD_A_(0, 0); DSRD_B_(0, 0);
    STAGE_A_(1, 0, t + 1);
    BARx(); PRIO1(); MMA_Q_(0, 0); PRIO0(); BARx();

    DSRD_B_(0, 1);
    STAGE_A_(1, 1, t + 1);
    BARx(); PRIO1(); MMA_Q_(0, 1); PRIO0(); BARx();

    DSRD_A_(0, 1);
    BARx(); PRIO1(); MMA_Q_(1, 0); PRIO0(); BARx();

    BARx(); PRIO1(); MMA_Q_(1, 1); PRIO0();
    VMW0();
    BARx();

    DSRD_A_(1, 0); DSRD_B_(1, 0);
    BARx(); PRIO1(); MMA_Q_(0, 0); PRIO0(); BARx();

    DSRD_B_(1, 1);
    BARx(); PRIO1(); MMA_Q_(0, 1); PRIO0(); BARx();

    DSRD_A_(1, 1);
    BARx(); PRIO1(); MMA_Q_(1, 0); PRIO0(); BARx();

    MMA_Q_(1, 1);
  }

  // ---- epilogue ----
  const int row0 = m0 + wr * 128 + (lane >> 4) * 4;
  const int col0 = n0 + wc * 64 + al;
  #pragma unroll
  for (int j = 0; j < 4; ++j) {
    const int col = col0 + j * 16;
    float bv = 0.f;
    if (HAS_BIAS) bv = bias[col];
    #pragma unroll
    for (int i = 0; i < 8; ++i) {
      #pragma unroll
      for (int r2 = 0; r2 < 4; ++r2) {
        float v = acc[i][j][r2] + bv;
        size_t o = (size_t)(row0 + i * 16 + r2) * N + col;
        if (OUT_BF16) ((unsigned short*)outp)[o] = f2bf(v);
        else          ((float*)outp)[o] = v;
      }
    }
  }
#undef STAGE_A_
#undef STAGE_B_
#undef DSRD_A_
#undef DSRD_B_
#undef MMA_Q_
#undef BARx
#undef VMW4
#undef VMW0
#undef PRIO1
#undef PRIO0
}

// ---------- scan kernels ----------
__global__ __launch_bounds__(256) void local_scan(
    float* __restrict__ xs, float* __restrict__ carry,
    const float* __restrict__ A_re, const float* __restrict__ A_im)
{
  int t = blockIdx.x * 256 + threadIdx.x;  // 8192 = B(2)*chunks(16)*S(256)
  int s = t & 255;
  int chunk = (t >> 8) & 15;
  int b = t >> 12;
  float ar = A_re[s], ai = A_im[s];
  float xr = 0.f, xi = 0.f;
  size_t base = ((size_t)(b * 2048 + chunk * 128)) * 512 + s;
  for (int j = 0; j < 128; ++j) {
    float ur = xs[base], ui = xs[base + 256];
    float nr = fmaf(ar, xr, fmaf(-ai, xi, ur));
    float ni = fmaf(ar, xi, fmaf(ai, xr, ui));
    xs[base] = nr; xs[base + 256] = ni;
    xr = nr; xi = ni;
    base += 512;
  }
  int ci = (b * 16 + chunk) * 512 + s;
  carry[ci] = xr; carry[ci + 256] = xi;
}

__global__ __launch_bounds__(256) void carry_scan(
    const float* __restrict__ A_re, const float* __restrict__ A_im,
    const float* __restrict__ carry, float* __restrict__ state_before,
    float* __restrict__ Apow)
{
  int s = threadIdx.x;  // 0..255
  float ar = A_re[s], ai = A_im[s];
  float pr = 1.f, pi = 0.f;
  for (int t = 0; t <= 128; ++t) {
    Apow[t * 512 + s] = pr; Apow[t * 512 + 256 + s] = pi;
    float nr = pr * ar - pi * ai;
    float ni = pr * ai + pi * ar;
    pr = nr; pi = ni;
  }
  float cr = Apow[128 * 512 + s], ci = Apow[128 * 512 + 256 + s];  // A^128
  for (int b = 0; b < 2; ++b) {
    float str = 0.f, sti = 0.f;
    for (int c = 0; c < 16; ++c) {
      int idx = (b * 16 + c) * 512 + s;
      state_before[idx] = str; state_before[idx + 256] = sti;
      float lr = carry[idx], li = carry[idx + 256];
      float nr = lr + cr * str - ci * sti;
      float ni = li + cr * sti + ci * str;
      str = nr; sti = ni;
    }
  }
}

__global__ __launch_bounds__(256) void combine_cast(
    const float* __restrict__ xs, const float* __restrict__ state_before,
    const float* __restrict__ Apow, unsigned short* __restrict__ xs_cat)
{
  int t = blockIdx.x * 256 + threadIdx.x;  // 4096*256
  int s = t & 255, row = t >> 8;
  int l = row & 2047, b = row >> 11;
  int chunk = l >> 7, j = l & 127;
  size_t o = (size_t)row * 512 + s;
  float xr = xs[o], xi = xs[o + 256];
  int sbi = (b * 16 + chunk) * 512 + s;
  float sr = state_before[sbi], si = state_before[sbi + 256];
  int api = (j + 1) * 512 + s;
  float pr = Apow[api], pi = Apow[api + 256];
  float fr = xr + pr * sr - pi * si;
  float fi = xi + pr * si + pi * sr;
  xs_cat[o] = f2bf(fr); xs_cat[o + 256] = f2bf(fi);
}

// ---------- launch ----------
extern "C" void kernel_launch(void* const* d_in, const int* in_sizes, int n_in,
                              void* d_out, int out_size, void* d_ws, size_t ws_size,
                              hipStream_t stream) {
  (void)in_sizes; (void)n_in; (void)out_size; (void)ws_size;
  const int*   ids    = (const int*)d_in[0];
  const float* emb    = (const float*)d_in[1];
  const float* w1     = (const float*)d_in[2];
  const float* w2     = (const float*)d_in[3];
  const float* A_re   = (const float*)d_in[4];
  const float* A_im   = (const float*)d_in[5];
  const float* B_re   = (const float*)d_in[6];
  const float* B_im   = (const float*)d_in[7];
  const float* C_re   = (const float*)d_in[8];
  const float* C_im   = (const float*)d_in[9];
  const float* D_p    = (const float*)d_in[10];
  const float* head_w = (const float*)d_in[11];
  const float* head_b = (const float*)d_in[12];
  float* out = (float*)d_out;

  char* ob = (char*)d_out;
  unsigned short* u_bf   = (unsigned short*)(ob + 0);         //  8,388,608 B
  unsigned short* BcatT  = (unsigned short*)(ob + 8388608);   //  1,048,576 B
  float* uBxs            = (float*)(ob + 9437184);            //  8,388,608 B
  float* carry           = (float*)(ob + 17825792);           //     65,536 B
  float* state_before    = (float*)(ob + 17891328);           //     65,536 B
  float* Apow            = (float*)(ob + 17956864);           //    264,192 B
  unsigned short* xs_cat = (unsigned short*)(ob + 18221056);  //  4,194,304 B
  unsigned short* CcatT  = (unsigned short*)(ob + 22415360);  //  1,048,576 B

  char* wb = (char*)d_ws;
  unsigned short* head_wT = (unsigned short*)(wb + 0);        // 65,536,000 B
  unsigned short* y_bf    = (unsigned short*)(wb + 65536000); //  8,388,608 B

  embed_norm<<<4096, 256, 0, stream>>>(ids, emb, w1, w2, u_bf);
  pack_B<<<2048, 256, 0, stream>>>(B_re, B_im, BcatT);
  pack_C<<<2048, 256, 0, stream>>>(C_re, C_im, CcatT);
  transpose_cvt<<<dim3(1000, 32), dim3(32, 8), 0, stream>>>(head_w, head_wT, 1024, 32000);

  // uB = u @ Bcat   [4096,1024]x[1024,512] -> fp32 (consumed by scan)
  gemm_bt<false, false><<<128, 256, 0, stream>>>(u_bf, BcatT, nullptr, uBxs, 4096, 512, 1024);

  local_scan<<<32, 256, 0, stream>>>(uBxs, carry, A_re, A_im);
  carry_scan<<<1, 256, 0, stream>>>(A_re, A_im, carry, state_before, Apow);
  combine_cast<<<4096, 256, 0, stream>>>(uBxs, state_before, Apow, xs_cat);

  // y = Re(xs @ C) + D_p   [4096,512]x[512,1024] -> bf16
  gemm_bt<true, true><<<256, 256, 0, stream>>>(xs_cat, CcatT, D_p, y_bf, 4096, 1024, 512);

  // out = y @ head_w + head_b   [4096,1024]x[1024,32000] -> fp32
  gemm256_bt<false, true><<<2000, 512, 0, stream>>>(y_bf, head_wT, head_b, out, 4096, 32000, 1024);
}